// Round 2
// baseline (327.489 us; speedup 1.0000x reference)
//
#include <hip/hip_runtime.h>
#include <hip/hip_bf16.h>
#include <math.h>

#define NEG_SLOPE 0.01f

__device__ __forceinline__ float lrelu(float v) {
    return v > 0.0f ? v : NEG_SLOPE * v;
}

// ---------------------------------------------------------------------------
// Transpose W1 [k=128][j=128] -> w1t [j=128][k=128] so per-node inner loops
// read W1T rows at wave-uniform, contiguous addresses (scalar-load friendly).
// ---------------------------------------------------------------------------
__global__ void k_transpose(const float* __restrict__ W1, float* __restrict__ w1t) {
    int t = blockIdx.x * blockDim.x + threadIdx.x; // 0..16383
    int j = t >> 7, k = t & 127;
    w1t[j * 128 + k] = W1[k * 128 + j];
}

// ---------------------------------------------------------------------------
// Per-node attention logit: s[n] = dot(lrelu(X[n,:] @ W1 + b1), W2) + b2
// 2 threads per node (each owns 64 of the 128 hidden units); X row held in
// VGPRs (launch_bounds(256,1) lifts the register cap so it stays resident).
// W rows are wave-uniform -> scalar loads feeding v_fma's SGPR operand.
// ---------------------------------------------------------------------------
__global__ void __launch_bounds__(256, 1) k_node_score(
    const float* __restrict__ X, const float* __restrict__ w1t,
    const float* __restrict__ b1, const float* __restrict__ W2,
    const float* __restrict__ b2, float* __restrict__ sarr, int N) {
    int t = threadIdx.x;
    int node = blockIdx.x * 128 + (t & 127);
    int jh = t >> 7;                       // which half of the hidden units
    bool valid = node < N;

    float4 x4[32];
    const float4* X4 = (const float4*)(X + (size_t)(valid ? node : 0) * 128);
#pragma unroll
    for (int i = 0; i < 32; ++i) x4[i] = X4[i];

    float s = 0.0f;
    int j0 = jh * 64;
#pragma unroll 2
    for (int j = j0; j < j0 + 64; ++j) {
        const float* wr = w1t + j * 128;   // wave-uniform address
        float a0 = 0.f, a1 = 0.f, a2 = 0.f, a3 = 0.f;
#pragma unroll
        for (int k4 = 0; k4 < 32; ++k4) {
            float4 xv = x4[k4];
            a0 += xv.x * wr[4 * k4 + 0];
            a1 += xv.y * wr[4 * k4 + 1];
            a2 += xv.z * wr[4 * k4 + 2];
            a3 += xv.w * wr[4 * k4 + 3];
        }
        float h = (a0 + a1) + (a2 + a3) + b1[j];
        s += lrelu(h) * W2[j];
    }

    __shared__ float part[256];
    part[t] = s;
    __syncthreads();
    if (t < 128 && valid)
        sarr[node] = part[t] + part[t + 128] + b2[0];
}

// ---------------------------------------------------------------------------
// Per-edge member-range offsets from sorted edge_ids. off has E+1 entries:
// off[e] = first member index with edge_ids >= e. Handles empty edges.
// ---------------------------------------------------------------------------
__global__ void k_edge_offsets(const int* __restrict__ edge_ids,
                               int* __restrict__ off, int M, int E) {
    int m = blockIdx.x * blockDim.x + threadIdx.x;
    if (m >= M) return;
    int e = edge_ids[m];
    if (m == 0) {
        for (int q = 0; q <= e; ++q) off[q] = 0;
    } else {
        int p = edge_ids[m - 1];
        for (int q = p + 1; q <= e; ++q) off[q] = m;
    }
    if (m == M - 1) {
        for (int q = e + 1; q <= E; ++q) off[q] = M;
    }
}

// ---------------------------------------------------------------------------
// One wave per edge: segment softmax over member logits, weighted gather-sum
// of X rows, fused leaky_relu + tanh epilogue. Writes beta and tanh(lrelu(Z)).
// ---------------------------------------------------------------------------
__global__ void __launch_bounds__(64) k_edge_softmax_agg(
    const float* __restrict__ X, const float* __restrict__ sarr,
    const int* __restrict__ node_idx, const int* __restrict__ off,
    float* __restrict__ outZ, float* __restrict__ outBeta) {
    int e = blockIdx.x;
    int lane = threadIdx.x;
    int s0 = off[e], s1 = off[e + 1];
    int n = s1 - s0;

    __shared__ float bs[64];
    __shared__ int ns[64];

    // phase 1: segment max of logits
    float wmax = -INFINITY;
    for (int i = lane; i < n; i += 64)
        wmax = fmaxf(wmax, sarr[node_idx[s0 + i]]);
#pragma unroll
    for (int d = 1; d < 64; d <<= 1)
        wmax = fmaxf(wmax, __shfl_xor(wmax, d, 64));

    // phase 2: segment sum of exp
    float sum = 0.0f;
    for (int i = lane; i < n; i += 64)
        sum += expf(sarr[node_idx[s0 + i]] - wmax);
#pragma unroll
    for (int d = 1; d < 64; d <<= 1)
        sum += __shfl_xor(sum, d, 64);
    float inv = (n > 0) ? 1.0f / sum : 0.0f;

    // phase 3: beta + weighted row accumulation (lane owns dims 2l, 2l+1)
    float az = 0.0f, aw = 0.0f;
    const float2* X2 = (const float2*)X;
    for (int base = 0; base < n; base += 64) {
        int cnt = min(64, n - base);
        if (lane < cnt) {
            int idx = node_idx[s0 + base + lane];
            float b = expf(sarr[idx] - wmax) * inv;
            outBeta[s0 + base + lane] = b;
            bs[lane] = b;
            ns[lane] = idx;
        }
        __syncthreads();
        for (int t = 0; t < cnt; ++t) {
            float b = bs[t];
            float2 xv = X2[(size_t)ns[t] * 64 + lane];
            az += b * xv.x;
            aw += b * xv.y;
        }
        __syncthreads();
    }

    outZ[(size_t)e * 128 + 2 * lane]     = tanhf(lrelu(az));
    outZ[(size_t)e * 128 + 2 * lane + 1] = tanhf(lrelu(aw));
}

extern "C" void kernel_launch(void* const* d_in, const int* in_sizes, int n_in,
                              void* d_out, int out_size, void* d_ws, size_t ws_size,
                              hipStream_t stream) {
    const float* X  = (const float*)d_in[0];
    const float* W1 = (const float*)d_in[1];
    const float* b1 = (const float*)d_in[2];
    const float* W2 = (const float*)d_in[3];
    const float* b2 = (const float*)d_in[4];
    const int* node_idx = (const int*)d_in[5];
    const int* edge_ids = (const int*)d_in[6];

    int N = in_sizes[0] / 128;          // 100000 nodes
    int M = in_sizes[5];                // 640000 memberships
    int E = (out_size - M) / 128;       // 20000 hyperedges

    // workspace layout: w1t [128*128] | sarr [N] | off [E+1] (ints)
    float* w1t  = (float*)d_ws;
    float* sarr = w1t + 128 * 128;
    int*   off  = (int*)(sarr + N);

    float* outZ    = (float*)d_out;
    float* outBeta = outZ + (size_t)E * 128;

    k_transpose<<<64, 256, 0, stream>>>(W1, w1t);
    k_node_score<<<(N + 127) / 128, 256, 0, stream>>>(X, w1t, b1, W2, b2, sarr, N);
    k_edge_offsets<<<(M + 255) / 256, 256, 0, stream>>>(edge_ids, off, M, E);
    k_edge_softmax_agg<<<E, 64, 0, stream>>>(X, sarr, node_idx, off, outZ, outBeta);
}

// Round 3
// 75.262 us; speedup vs baseline: 4.3513x; 4.3513x over previous
//
#include <hip/hip_runtime.h>
#include <hip/hip_bf16.h>
#include <math.h>

#define NEG_SLOPE 0.01f

typedef __attribute__((ext_vector_type(8))) short bf16x8;
typedef __attribute__((ext_vector_type(4))) float f32x4;

__device__ __forceinline__ float lrelu(float v) {
    return v > 0.0f ? v : NEG_SLOPE * v;
}

__device__ __forceinline__ short f2bf(float f) {
    __hip_bfloat16 h = __float2bfloat16(f);
    return *reinterpret_cast<short*>(&h);
}

// ---------------------------------------------------------------------------
// Pre-arrange W1 (fp32 [k=128][j=128]) into bf16 MFMA B-fragments:
// w1f[(jt*4+kc)*64 + lane][e] = W1[k = kc*32 + (lane>>4)*8 + e][j = jt*16 + (lane&15)]
// so each lane's B-frag is one contiguous 16-byte ds_read_b128.
// ---------------------------------------------------------------------------
__global__ void k_prep_w1(const float* __restrict__ W1, short* __restrict__ w1f) {
    int t = blockIdx.x * blockDim.x + threadIdx.x;  // 0..2047
    if (t >= 2048) return;
    int lane = t & 63;
    int fc = t >> 6;                 // 0..31 = jt*4 + kc
    int jt = fc >> 2, kc = fc & 3;
    int col = lane & 15;
    int k0 = kc * 32 + (lane >> 4) * 8;
    short* dst = w1f + (size_t)t * 8;
#pragma unroll
    for (int e = 0; e < 8; ++e)
        dst[e] = f2bf(W1[(size_t)(k0 + e) * 128 + jt * 16 + col]);
}

// ---------------------------------------------------------------------------
// Node scores via MFMA: s[n] = dot(lrelu(X[n,:]@W1 + b1), W2) + b2.
// 4 waves/block, 16 nodes/wave (64 nodes/block). W1 frags staged in LDS.
// A-frag: lane holds X[n0 + (l&15)][kc*32 + (l>>4)*8 + e]  (8 bf16 = 4 VGPR)
// D-frag: lane l, reg i -> h[node=(l>>4)*4+i][j = jt*16 + (l&15)]
// Epilogue: +b1, lrelu, *W2, sum over j (reg + 16-lane shfl_xor reduce).
// ---------------------------------------------------------------------------
__global__ void __launch_bounds__(256) k_node_score_mfma(
    const float* __restrict__ X, const short* __restrict__ w1f,
    const float* __restrict__ b1, const float* __restrict__ W2,
    const float* __restrict__ b2, float* __restrict__ sarr, int N) {
    __shared__ short w1s[32 * 64 * 8];  // 32 KB

    int tid = threadIdx.x;
    {   // stage all 32 B-frags (32768 B) into LDS, coalesced float4 copies
        const float4* src = (const float4*)w1f;
        float4* dst = (float4*)w1s;
#pragma unroll
        for (int i = 0; i < 8; ++i) dst[tid + 256 * i] = src[tid + 256 * i];
    }
    __syncthreads();

    int wid = tid >> 6, lane = tid & 63;
    int c15 = lane & 15, g = lane >> 4;
    int n0 = blockIdx.x * 64 + wid * 16;

    // A-fragments: this lane reads row (n0 + c15), k-chunk kc, 8 floats
    int arow = n0 + c15;
    const float* xr = X + (size_t)(arow < N ? arow : N - 1) * 128 + g * 8;
    bf16x8 afr[4];
#pragma unroll
    for (int kc = 0; kc < 4; ++kc) {
        float4 f0 = *(const float4*)(xr + kc * 32);
        float4 f1 = *(const float4*)(xr + kc * 32 + 4);
        bf16x8 a;
        a[0] = f2bf(f0.x); a[1] = f2bf(f0.y); a[2] = f2bf(f0.z); a[3] = f2bf(f0.w);
        a[4] = f2bf(f1.x); a[5] = f2bf(f1.y); a[6] = f2bf(f1.z); a[7] = f2bf(f1.w);
        afr[kc] = a;
    }

    // per-lane bias / W2 for column c15 of each j-tile
    float b1v[8], w2v[8];
#pragma unroll
    for (int jt = 0; jt < 8; ++jt) {
        b1v[jt] = b1[jt * 16 + c15];
        w2v[jt] = W2[jt * 16 + c15];
    }

    float sv[4] = {0.f, 0.f, 0.f, 0.f};
#pragma unroll
    for (int jt = 0; jt < 8; ++jt) {
        f32x4 acc = {0.f, 0.f, 0.f, 0.f};
#pragma unroll
        for (int kc = 0; kc < 4; ++kc) {
            bf16x8 bfr = *(const bf16x8*)(w1s + ((jt * 4 + kc) * 64 + lane) * 8);
            acc = __builtin_amdgcn_mfma_f32_16x16x32_bf16(afr[kc], bfr, acc, 0, 0, 0);
        }
#pragma unroll
        for (int i = 0; i < 4; ++i) {
            float h = acc[i] + b1v[jt];
            h = h > 0.f ? h : NEG_SLOPE * h;
            sv[i] += h * w2v[jt];
        }
    }

    // reduce over the 16 column-lanes (j distributed across c15)
#pragma unroll
    for (int d = 1; d < 16; d <<= 1) {
#pragma unroll
        for (int i = 0; i < 4; ++i) sv[i] += __shfl_xor(sv[i], d, 64);
    }
    if (c15 == 0) {
        float bb = b2[0];
#pragma unroll
        for (int i = 0; i < 4; ++i) {
            int node = n0 + g * 4 + i;
            if (node < N) sarr[node] = sv[i] + bb;
        }
    }
}

// ---------------------------------------------------------------------------
// Per-edge member-range offsets from sorted edge_ids. off has E+1 entries.
// ---------------------------------------------------------------------------
__global__ void k_edge_offsets(const int* __restrict__ edge_ids,
                               int* __restrict__ off, int M, int E) {
    int m = blockIdx.x * blockDim.x + threadIdx.x;
    if (m >= M) return;
    int e = edge_ids[m];
    if (m == 0) {
        for (int q = 0; q <= e; ++q) off[q] = 0;
    } else {
        int p = edge_ids[m - 1];
        for (int q = p + 1; q <= e; ++q) off[q] = m;
    }
    if (m == M - 1) {
        for (int q = e + 1; q <= E; ++q) off[q] = M;
    }
}

// ---------------------------------------------------------------------------
// One wave per edge: segment softmax over member logits, weighted gather-sum
// of X rows, fused leaky_relu + tanh epilogue. Writes beta and tanh(lrelu(Z)).
// ---------------------------------------------------------------------------
__global__ void __launch_bounds__(64) k_edge_softmax_agg(
    const float* __restrict__ X, const float* __restrict__ sarr,
    const int* __restrict__ node_idx, const int* __restrict__ off,
    float* __restrict__ outZ, float* __restrict__ outBeta) {
    int e = blockIdx.x;
    int lane = threadIdx.x;
    int s0 = off[e], s1 = off[e + 1];
    int n = s1 - s0;

    __shared__ float bs[64];
    __shared__ int ns[64];

    // phase 1: segment max of logits
    float wmax = -INFINITY;
    for (int i = lane; i < n; i += 64)
        wmax = fmaxf(wmax, sarr[node_idx[s0 + i]]);
#pragma unroll
    for (int d = 1; d < 64; d <<= 1)
        wmax = fmaxf(wmax, __shfl_xor(wmax, d, 64));

    // phase 2: segment sum of exp
    float sum = 0.0f;
    for (int i = lane; i < n; i += 64)
        sum += expf(sarr[node_idx[s0 + i]] - wmax);
#pragma unroll
    for (int d = 1; d < 64; d <<= 1)
        sum += __shfl_xor(sum, d, 64);
    float inv = (n > 0) ? 1.0f / sum : 0.0f;

    // phase 3: beta + weighted row accumulation (lane owns dims 2l, 2l+1)
    float az = 0.0f, aw = 0.0f;
    const float2* X2 = (const float2*)X;
    for (int base = 0; base < n; base += 64) {
        int cnt = min(64, n - base);
        if (lane < cnt) {
            int idx = node_idx[s0 + base + lane];
            float b = expf(sarr[idx] - wmax) * inv;
            outBeta[s0 + base + lane] = b;
            bs[lane] = b;
            ns[lane] = idx;
        }
        __syncthreads();
        for (int t = 0; t < cnt; ++t) {
            float b = bs[t];
            float2 xv = X2[(size_t)ns[t] * 64 + lane];
            az += b * xv.x;
            aw += b * xv.y;
        }
        __syncthreads();
    }

    outZ[(size_t)e * 128 + 2 * lane]     = tanhf(lrelu(az));
    outZ[(size_t)e * 128 + 2 * lane + 1] = tanhf(lrelu(aw));
}

extern "C" void kernel_launch(void* const* d_in, const int* in_sizes, int n_in,
                              void* d_out, int out_size, void* d_ws, size_t ws_size,
                              hipStream_t stream) {
    const float* X  = (const float*)d_in[0];
    const float* W1 = (const float*)d_in[1];
    const float* b1 = (const float*)d_in[2];
    const float* W2 = (const float*)d_in[3];
    const float* b2 = (const float*)d_in[4];
    const int* node_idx = (const int*)d_in[5];
    const int* edge_ids = (const int*)d_in[6];

    int N = in_sizes[0] / 128;          // 100000 nodes
    int M = in_sizes[5];                // 640000 memberships
    int E = (out_size - M) / 128;       // 20000 hyperedges

    // workspace layout: w1f [32KB bf16 frags] | sarr [N floats] | off [E+1 ints]
    short* w1f  = (short*)d_ws;
    float* sarr = (float*)((char*)d_ws + 32768);
    int*   off  = (int*)(sarr + N);

    float* outZ    = (float*)d_out;
    float* outBeta = outZ + (size_t)E * 128;

    k_prep_w1<<<8, 256, 0, stream>>>(W1, w1f);
    k_node_score_mfma<<<(N + 63) / 64, 256, 0, stream>>>(X, w1f, b1, W2, b2, sarr, N);
    k_edge_offsets<<<(M + 255) / 256, 256, 0, stream>>>(edge_ids, off, M, E);
    k_edge_softmax_agg<<<E, 64, 0, stream>>>(X, sarr, node_idx, off, outZ, outBeta);
}

// Round 4
// 65.739 us; speedup vs baseline: 4.9817x; 1.1449x over previous
//
#include <hip/hip_runtime.h>
#include <hip/hip_bf16.h>
#include <math.h>

#define NEG_SLOPE 0.01f

typedef __attribute__((ext_vector_type(8))) short bf16x8;
typedef __attribute__((ext_vector_type(4))) float f32x4;

__device__ __forceinline__ float lrelu(float v) {
    return v > 0.0f ? v : NEG_SLOPE * v;
}

__device__ __forceinline__ short f2bf(float f) {
    __hip_bfloat16 h = __float2bfloat16(f);
    return *reinterpret_cast<short*>(&h);
}

// ---------------------------------------------------------------------------
// Pre-arrange W1 (fp32 [k=128][j=128]) into bf16 MFMA B-fragments:
// w1f[(jt*4+kc)*64 + lane][e] = W1[k = kc*32 + (lane>>4)*8 + e][j = jt*16 + (lane&15)]
// ---------------------------------------------------------------------------
__global__ void k_prep_w1(const float* __restrict__ W1, short* __restrict__ w1f) {
    int t = blockIdx.x * blockDim.x + threadIdx.x;  // 0..2047
    if (t >= 2048) return;
    int lane = t & 63;
    int fc = t >> 6;                 // 0..31 = jt*4 + kc
    int jt = fc >> 2, kc = fc & 3;
    int col = lane & 15;
    int k0 = kc * 32 + (lane >> 4) * 8;
    short* dst = w1f + (size_t)t * 8;
#pragma unroll
    for (int e = 0; e < 8; ++e)
        dst[e] = f2bf(W1[(size_t)(k0 + e) * 128 + jt * 16 + col]);
}

// ---------------------------------------------------------------------------
// Node scores via MFMA + side-product bf16 copy of X (row-major [N][128]).
// A-frag: lane holds X[n0 + (l&15)][kc*32 + (l>>4)*8 + e]; those same bf16
// values are stored to Xb (free conversion — X is already being read).
// ---------------------------------------------------------------------------
__global__ void __launch_bounds__(256) k_node_score_mfma(
    const float* __restrict__ X, const short* __restrict__ w1f,
    const float* __restrict__ b1, const float* __restrict__ W2,
    const float* __restrict__ b2, float* __restrict__ sarr,
    unsigned short* __restrict__ Xb, int N) {
    __shared__ short w1s[32 * 64 * 8];  // 32 KB

    int tid = threadIdx.x;
    {   // stage all 32 B-frags (32768 B) into LDS, coalesced float4 copies
        const float4* src = (const float4*)w1f;
        float4* dst = (float4*)w1s;
#pragma unroll
        for (int i = 0; i < 8; ++i) dst[tid + 256 * i] = src[tid + 256 * i];
    }
    __syncthreads();

    int wid = tid >> 6, lane = tid & 63;
    int c15 = lane & 15, g = lane >> 4;
    int n0 = blockIdx.x * 64 + wid * 16;

    int arow = n0 + c15;
    size_t srow = (size_t)(arow < N ? arow : N - 1);
    const float* xr = X + srow * 128 + g * 8;
    bf16x8 afr[4];
#pragma unroll
    for (int kc = 0; kc < 4; ++kc) {
        float4 f0 = *(const float4*)(xr + kc * 32);
        float4 f1 = *(const float4*)(xr + kc * 32 + 4);
        bf16x8 a;
        a[0] = f2bf(f0.x); a[1] = f2bf(f0.y); a[2] = f2bf(f0.z); a[3] = f2bf(f0.w);
        a[4] = f2bf(f1.x); a[5] = f2bf(f1.y); a[6] = f2bf(f1.z); a[7] = f2bf(f1.w);
        afr[kc] = a;
        if (Xb)  // free bf16 X copy for the gather kernel
            *(bf16x8*)(Xb + srow * 128 + kc * 32 + g * 8) = a;
    }

    float b1v[8], w2v[8];
#pragma unroll
    for (int jt = 0; jt < 8; ++jt) {
        b1v[jt] = b1[jt * 16 + c15];
        w2v[jt] = W2[jt * 16 + c15];
    }

    float sv[4] = {0.f, 0.f, 0.f, 0.f};
#pragma unroll
    for (int jt = 0; jt < 8; ++jt) {
        f32x4 acc = {0.f, 0.f, 0.f, 0.f};
#pragma unroll
        for (int kc = 0; kc < 4; ++kc) {
            bf16x8 bfr = *(const bf16x8*)(w1s + ((jt * 4 + kc) * 64 + lane) * 8);
            acc = __builtin_amdgcn_mfma_f32_16x16x32_bf16(afr[kc], bfr, acc, 0, 0, 0);
        }
#pragma unroll
        for (int i = 0; i < 4; ++i) {
            float h = acc[i] + b1v[jt];
            h = h > 0.f ? h : NEG_SLOPE * h;
            sv[i] += h * w2v[jt];
        }
    }

#pragma unroll
    for (int d = 1; d < 16; d <<= 1) {
#pragma unroll
        for (int i = 0; i < 4; ++i) sv[i] += __shfl_xor(sv[i], d, 64);
    }
    if (c15 == 0) {
        float bb = b2[0];
#pragma unroll
        for (int i = 0; i < 4; ++i) {
            int node = n0 + g * 4 + i;
            if (node < N) sarr[node] = sv[i] + bb;
        }
    }
}

// ---------------------------------------------------------------------------
// Per-edge member-range offsets from sorted edge_ids. off has E+1 entries.
// ---------------------------------------------------------------------------
__global__ void k_edge_offsets(const int* __restrict__ edge_ids,
                               int* __restrict__ off, int M, int E) {
    int m = blockIdx.x * blockDim.x + threadIdx.x;
    if (m >= M) return;
    int e = edge_ids[m];
    if (m == 0) {
        for (int q = 0; q <= e; ++q) off[q] = 0;
    } else {
        int p = edge_ids[m - 1];
        for (int q = p + 1; q <= e; ++q) off[q] = m;
    }
    if (m == M - 1) {
        for (int q = e + 1; q <= E; ++q) off[q] = M;
    }
}

// ---------------------------------------------------------------------------
// One wave per edge: segment softmax + weighted gather-sum + lrelu/tanh.
// BF=1: gather rows from bf16 Xb (4 B/lane, 256 B/row); BF=0: f32 X fallback.
// ---------------------------------------------------------------------------
template <int BF>
__global__ void __launch_bounds__(64) k_edge_agg(
    const float* __restrict__ X, const unsigned short* __restrict__ Xb,
    const float* __restrict__ sarr, const int* __restrict__ node_idx,
    const int* __restrict__ off, float* __restrict__ outZ,
    float* __restrict__ outBeta) {
    int e = blockIdx.x;
    int lane = threadIdx.x;
    int s0 = off[e], s1 = off[e + 1];
    int n = s1 - s0;

    __shared__ float bs[64];
    __shared__ int ns[64];

    // phase 1: segment max of logits
    float wmax = -INFINITY;
    for (int i = lane; i < n; i += 64)
        wmax = fmaxf(wmax, sarr[node_idx[s0 + i]]);
#pragma unroll
    for (int d = 1; d < 64; d <<= 1)
        wmax = fmaxf(wmax, __shfl_xor(wmax, d, 64));

    // phase 2: segment sum of exp
    float sum = 0.0f;
    for (int i = lane; i < n; i += 64)
        sum += expf(sarr[node_idx[s0 + i]] - wmax);
#pragma unroll
    for (int d = 1; d < 64; d <<= 1)
        sum += __shfl_xor(sum, d, 64);
    float inv = (n > 0) ? 1.0f / sum : 0.0f;

    // phase 3: beta + weighted row accumulation (lane owns dims 2l, 2l+1)
    float az0 = 0.f, aw0 = 0.f, az1 = 0.f, aw1 = 0.f;
    const float2* X2 = (const float2*)X;
    for (int base = 0; base < n; base += 64) {
        int cnt = min(64, n - base);
        if (lane < cnt) {
            int idx = node_idx[s0 + base + lane];
            float b = expf(sarr[idx] - wmax) * inv;
            outBeta[s0 + base + lane] = b;
            bs[lane] = b;
            ns[lane] = idx;
        }
        __syncthreads();
        int t = 0;
        for (; t + 1 < cnt; t += 2) {
            if (BF) {
                unsigned int v0 = ((const unsigned int*)(Xb + (size_t)ns[t] * 128))[lane];
                unsigned int v1 = ((const unsigned int*)(Xb + (size_t)ns[t + 1] * 128))[lane];
                float b0 = bs[t], b1_ = bs[t + 1];
                az0 += b0 * __uint_as_float(v0 << 16);
                aw0 += b0 * __uint_as_float(v0 & 0xffff0000u);
                az1 += b1_ * __uint_as_float(v1 << 16);
                aw1 += b1_ * __uint_as_float(v1 & 0xffff0000u);
            } else {
                float2 xv0 = X2[(size_t)ns[t] * 64 + lane];
                float2 xv1 = X2[(size_t)ns[t + 1] * 64 + lane];
                az0 += bs[t] * xv0.x;
                aw0 += bs[t] * xv0.y;
                az1 += bs[t + 1] * xv1.x;
                aw1 += bs[t + 1] * xv1.y;
            }
        }
        if (t < cnt) {
            if (BF) {
                unsigned int v0 = ((const unsigned int*)(Xb + (size_t)ns[t] * 128))[lane];
                az0 += bs[t] * __uint_as_float(v0 << 16);
                aw0 += bs[t] * __uint_as_float(v0 & 0xffff0000u);
            } else {
                float2 xv0 = X2[(size_t)ns[t] * 64 + lane];
                az0 += bs[t] * xv0.x;
                aw0 += bs[t] * xv0.y;
            }
        }
        __syncthreads();
    }

    float az = az0 + az1, aw = aw0 + aw1;
    outZ[(size_t)e * 128 + 2 * lane]     = tanhf(lrelu(az));
    outZ[(size_t)e * 128 + 2 * lane + 1] = tanhf(lrelu(aw));
}

extern "C" void kernel_launch(void* const* d_in, const int* in_sizes, int n_in,
                              void* d_out, int out_size, void* d_ws, size_t ws_size,
                              hipStream_t stream) {
    const float* X  = (const float*)d_in[0];
    const float* W1 = (const float*)d_in[1];
    const float* b1 = (const float*)d_in[2];
    const float* W2 = (const float*)d_in[3];
    const float* b2 = (const float*)d_in[4];
    const int* node_idx = (const int*)d_in[5];
    const int* edge_ids = (const int*)d_in[6];

    int N = in_sizes[0] / 128;          // 100000 nodes
    int M = in_sizes[5];                // 640000 memberships
    int E = (out_size - M) / 128;       // 20000 hyperedges

    // workspace layout: w1f 32KB | sarr N f32 | off E+1 ints | Xb N*128 bf16
    char* p = (char*)d_ws;
    short* w1f  = (short*)p;
    float* sarr = (float*)(p + 32768);
    int*   off  = (int*)(p + 32768 + (size_t)N * 4);
    size_t xb_off = (32768 + (size_t)N * 4 + (size_t)(E + 1) * 4 + 255) & ~(size_t)255;
    unsigned short* Xb = (unsigned short*)(p + xb_off);
    bool useBF = ws_size >= xb_off + (size_t)N * 128 * 2;

    float* outZ    = (float*)d_out;
    float* outBeta = outZ + (size_t)E * 128;

    k_prep_w1<<<8, 256, 0, stream>>>(W1, w1f);
    k_node_score_mfma<<<(N + 63) / 64, 256, 0, stream>>>(
        X, w1f, b1, W2, b2, sarr, useBF ? Xb : (unsigned short*)nullptr, N);
    k_edge_offsets<<<(M + 255) / 256, 256, 0, stream>>>(edge_ids, off, M, E);
    if (useBF)
        k_edge_agg<1><<<E, 64, 0, stream>>>(X, Xb, sarr, node_idx, off, outZ, outBeta);
    else
        k_edge_agg<0><<<E, 64, 0, stream>>>(X, Xb, sarr, node_idx, off, outZ, outBeta);
}

// Round 5
// 59.498 us; speedup vs baseline: 5.5042x; 1.1049x over previous
//
#include <hip/hip_runtime.h>
#include <hip/hip_bf16.h>
#include <math.h>

#define NEG_SLOPE 0.01f

typedef __attribute__((ext_vector_type(8))) short bf16x8;
typedef __attribute__((ext_vector_type(4))) float f32x4;

__device__ __forceinline__ float lrelu(float v) {
    return v > 0.0f ? v : NEG_SLOPE * v;
}

__device__ __forceinline__ short f2bf(float f) {
    __hip_bfloat16 h = __float2bfloat16(f);
    return *reinterpret_cast<short*>(&h);
}

// ---------------------------------------------------------------------------
// Pre-arrange W1 (fp32 [k=128][j=128]) into bf16 MFMA B-fragments.
// ---------------------------------------------------------------------------
__global__ void k_prep_w1(const float* __restrict__ W1, short* __restrict__ w1f) {
    int t = blockIdx.x * blockDim.x + threadIdx.x;  // 0..2047
    if (t >= 2048) return;
    int lane = t & 63;
    int fc = t >> 6;                 // 0..31 = jt*4 + kc
    int jt = fc >> 2, kc = fc & 3;
    int col = lane & 15;
    int k0 = kc * 32 + (lane >> 4) * 8;
    short* dst = w1f + (size_t)t * 8;
#pragma unroll
    for (int e = 0; e < 8; ++e)
        dst[e] = f2bf(W1[(size_t)(k0 + e) * 128 + jt * 16 + col]);
}

// ---------------------------------------------------------------------------
// Node scores via MFMA + side-product bf16 copy of X (row-major [N][128]).
// ---------------------------------------------------------------------------
__global__ void __launch_bounds__(256) k_node_score_mfma(
    const float* __restrict__ X, const short* __restrict__ w1f,
    const float* __restrict__ b1, const float* __restrict__ W2,
    const float* __restrict__ b2, float* __restrict__ sarr,
    unsigned short* __restrict__ Xb, int N) {
    __shared__ short w1s[32 * 64 * 8];  // 32 KB

    int tid = threadIdx.x;
    {
        const float4* src = (const float4*)w1f;
        float4* dst = (float4*)w1s;
#pragma unroll
        for (int i = 0; i < 8; ++i) dst[tid + 256 * i] = src[tid + 256 * i];
    }
    __syncthreads();

    int wid = tid >> 6, lane = tid & 63;
    int c15 = lane & 15, g = lane >> 4;
    int n0 = blockIdx.x * 64 + wid * 16;

    int arow = n0 + c15;
    size_t srow = (size_t)(arow < N ? arow : N - 1);
    const float* xr = X + srow * 128 + g * 8;
    bf16x8 afr[4];
#pragma unroll
    for (int kc = 0; kc < 4; ++kc) {
        float4 f0 = *(const float4*)(xr + kc * 32);
        float4 f1 = *(const float4*)(xr + kc * 32 + 4);
        bf16x8 a;
        a[0] = f2bf(f0.x); a[1] = f2bf(f0.y); a[2] = f2bf(f0.z); a[3] = f2bf(f0.w);
        a[4] = f2bf(f1.x); a[5] = f2bf(f1.y); a[6] = f2bf(f1.z); a[7] = f2bf(f1.w);
        afr[kc] = a;
        if (Xb)
            *(bf16x8*)(Xb + srow * 128 + kc * 32 + g * 8) = a;
    }

    float b1v[8], w2v[8];
#pragma unroll
    for (int jt = 0; jt < 8; ++jt) {
        b1v[jt] = b1[jt * 16 + c15];
        w2v[jt] = W2[jt * 16 + c15];
    }

    float sv[4] = {0.f, 0.f, 0.f, 0.f};
#pragma unroll
    for (int jt = 0; jt < 8; ++jt) {
        f32x4 acc = {0.f, 0.f, 0.f, 0.f};
#pragma unroll
        for (int kc = 0; kc < 4; ++kc) {
            bf16x8 bfr = *(const bf16x8*)(w1s + ((jt * 4 + kc) * 64 + lane) * 8);
            acc = __builtin_amdgcn_mfma_f32_16x16x32_bf16(afr[kc], bfr, acc, 0, 0, 0);
        }
#pragma unroll
        for (int i = 0; i < 4; ++i) {
            float h = acc[i] + b1v[jt];
            h = h > 0.f ? h : NEG_SLOPE * h;
            sv[i] += h * w2v[jt];
        }
    }

#pragma unroll
    for (int d = 1; d < 16; d <<= 1) {
#pragma unroll
        for (int i = 0; i < 4; ++i) sv[i] += __shfl_xor(sv[i], d, 64);
    }
    if (c15 == 0) {
        float bb = b2[0];
#pragma unroll
        for (int i = 0; i < 4; ++i) {
            int node = n0 + g * 4 + i;
            if (node < N) sarr[node] = sv[i] + bb;
        }
    }
}

// ---------------------------------------------------------------------------
// Per-edge member-range offsets from sorted edge_ids. off has E+1 entries.
// ---------------------------------------------------------------------------
__global__ void k_edge_offsets(const int* __restrict__ edge_ids,
                               int* __restrict__ off, int M, int E) {
    int m = blockIdx.x * blockDim.x + threadIdx.x;
    if (m >= M) return;
    int e = edge_ids[m];
    if (m == 0) {
        for (int q = 0; q <= e; ++q) off[q] = 0;
    } else {
        int p = edge_ids[m - 1];
        for (int q = p + 1; q <= e; ++q) off[q] = m;
    }
    if (m == M - 1) {
        for (int q = e + 1; q <= E; ++q) off[q] = M;
    }
}

// ---------------------------------------------------------------------------
// 4-rows-per-iteration weighted accumulate: 16 lanes each own one row
// (group g = lane>>4 takes row t+g); lane covers cols c*8..c*8+7.
// BF=1: one uint4 (8 bf16) per lane; BF=0: two float4 from fp32 X.
// ---------------------------------------------------------------------------
template <int BF>
__device__ __forceinline__ void row4_acc(const float2* __restrict__ prw, int t,
                                         int g, int c,
                                         const unsigned short* __restrict__ Xb,
                                         const float* __restrict__ X,
                                         float* __restrict__ acc) {
    float2 p = prw[t + g];
    float b = p.x;
    int idx = __float_as_int(p.y);
    if (BF) {
        uint4 v = ((const uint4*)(Xb + (size_t)idx * 128))[c];
        acc[0] += b * __uint_as_float(v.x << 16);
        acc[1] += b * __uint_as_float(v.x & 0xffff0000u);
        acc[2] += b * __uint_as_float(v.y << 16);
        acc[3] += b * __uint_as_float(v.y & 0xffff0000u);
        acc[4] += b * __uint_as_float(v.z << 16);
        acc[5] += b * __uint_as_float(v.z & 0xffff0000u);
        acc[6] += b * __uint_as_float(v.w << 16);
        acc[7] += b * __uint_as_float(v.w & 0xffff0000u);
    } else {
        const float4* xr = (const float4*)(X + (size_t)idx * 128 + c * 8);
        float4 v0 = xr[0], v1 = xr[1];
        acc[0] += b * v0.x; acc[1] += b * v0.y;
        acc[2] += b * v0.z; acc[3] += b * v0.w;
        acc[4] += b * v1.x; acc[5] += b * v1.y;
        acc[6] += b * v1.z; acc[7] += b * v1.w;
    }
}

// ---------------------------------------------------------------------------
// One wave per edge, 4 edges per block. Fast path (n<=64): one sarr gather,
// one expf, butterfly softmax, zero barriers. Aggregation: 4 rows/iteration.
// ---------------------------------------------------------------------------
template <int BF>
__global__ void __launch_bounds__(256) k_edge_agg(
    const float* __restrict__ X, const unsigned short* __restrict__ Xb,
    const float* __restrict__ sarr, const int* __restrict__ node_idx,
    const int* __restrict__ off, float* __restrict__ outZ,
    float* __restrict__ outBeta, int E) {
    int wid = threadIdx.x >> 6, lane = threadIdx.x & 63;
    int e = blockIdx.x * 4 + wid;
    if (e >= E) return;

    __shared__ float2 prs[4][64];   // {beta, bitcast(idx)} per member slot
    float2* prw = prs[wid];

    int s0 = off[e], n = off[e + 1] - s0;
    int g = lane >> 4, c = lane & 15;
    float acc[8] = {0.f, 0.f, 0.f, 0.f, 0.f, 0.f, 0.f, 0.f};

    if (n <= 64) {
        int idxv = 0;
        float svv = -INFINITY;
        if (lane < n) {
            idxv = node_idx[s0 + lane];
            svv = sarr[idxv];
        }
        float m = svv;
#pragma unroll
        for (int d = 1; d < 64; d <<= 1) m = fmaxf(m, __shfl_xor(m, d, 64));
        float ex = (lane < n) ? expf(svv - m) : 0.f;
        float sum = ex;
#pragma unroll
        for (int d = 1; d < 64; d <<= 1) sum += __shfl_xor(sum, d, 64);
        float inv = (n > 0) ? 1.f / sum : 0.f;
        float beta = ex * inv;
        if (lane < n) outBeta[s0 + lane] = beta;
        prw[lane] = make_float2(beta, __int_as_float(idxv));
        // wave-local LDS write->read: lockstep wave, compiler inserts lgkmcnt
        for (int t = 0; t < n; t += 4)
            row4_acc<BF>(prw, t, g, c, Xb, X, acc);
    } else {
        // rare big-edge fallback (correctness path)
        float m = -INFINITY;
        for (int i = lane; i < n; i += 64)
            m = fmaxf(m, sarr[node_idx[s0 + i]]);
#pragma unroll
        for (int d = 1; d < 64; d <<= 1) m = fmaxf(m, __shfl_xor(m, d, 64));
        float sum = 0.f;
        for (int i = lane; i < n; i += 64)
            sum += expf(sarr[node_idx[s0 + i]] - m);
#pragma unroll
        for (int d = 1; d < 64; d <<= 1) sum += __shfl_xor(sum, d, 64);
        float inv = 1.f / sum;
        for (int base = 0; base < n; base += 64) {
            int cnt = min(64, n - base);
            int idxv = 0;
            float beta = 0.f;
            if (lane < cnt) {
                idxv = node_idx[s0 + base + lane];
                beta = expf(sarr[idxv] - m) * inv;
                outBeta[s0 + base + lane] = beta;
            }
            prw[lane] = make_float2(beta, __int_as_float(idxv));
            for (int t = 0; t < cnt; t += 4)
                row4_acc<BF>(prw, t, g, c, Xb, X, acc);
        }
    }

#pragma unroll
    for (int i = 0; i < 8; ++i) {
        acc[i] += __shfl_xor(acc[i], 16, 64);
        acc[i] += __shfl_xor(acc[i], 32, 64);
    }
    if (g == 0) {
        float4 o0, o1;
        o0.x = tanhf(lrelu(acc[0]));
        o0.y = tanhf(lrelu(acc[1]));
        o0.z = tanhf(lrelu(acc[2]));
        o0.w = tanhf(lrelu(acc[3]));
        o1.x = tanhf(lrelu(acc[4]));
        o1.y = tanhf(lrelu(acc[5]));
        o1.z = tanhf(lrelu(acc[6]));
        o1.w = tanhf(lrelu(acc[7]));
        float* zr = outZ + (size_t)e * 128 + c * 8;
        *(float4*)zr = o0;
        *(float4*)(zr + 4) = o1;
    }
}

extern "C" void kernel_launch(void* const* d_in, const int* in_sizes, int n_in,
                              void* d_out, int out_size, void* d_ws, size_t ws_size,
                              hipStream_t stream) {
    const float* X  = (const float*)d_in[0];
    const float* W1 = (const float*)d_in[1];
    const float* b1 = (const float*)d_in[2];
    const float* W2 = (const float*)d_in[3];
    const float* b2 = (const float*)d_in[4];
    const int* node_idx = (const int*)d_in[5];
    const int* edge_ids = (const int*)d_in[6];

    int N = in_sizes[0] / 128;          // 100000 nodes
    int M = in_sizes[5];                // 640000 memberships
    int E = (out_size - M) / 128;       // 20000 hyperedges

    // workspace: w1f 32KB | sarr N f32 | off E+1 ints | Xb N*128 bf16
    char* p = (char*)d_ws;
    short* w1f  = (short*)p;
    float* sarr = (float*)(p + 32768);
    int*   off  = (int*)(p + 32768 + (size_t)N * 4);
    size_t xb_off = (32768 + (size_t)N * 4 + (size_t)(E + 1) * 4 + 255) & ~(size_t)255;
    unsigned short* Xb = (unsigned short*)(p + xb_off);
    bool useBF = ws_size >= xb_off + (size_t)N * 128 * 2;

    float* outZ    = (float*)d_out;
    float* outBeta = outZ + (size_t)E * 128;

    k_prep_w1<<<8, 256, 0, stream>>>(W1, w1f);
    k_node_score_mfma<<<(N + 63) / 64, 256, 0, stream>>>(
        X, w1f, b1, W2, b2, sarr, useBF ? Xb : (unsigned short*)nullptr, N);
    k_edge_offsets<<<(M + 255) / 256, 256, 0, stream>>>(edge_ids, off, M, E);
    if (useBF)
        k_edge_agg<1><<<(E + 3) / 4, 256, 0, stream>>>(
            X, Xb, sarr, node_idx, off, outZ, outBeta, E);
    else
        k_edge_agg<0><<<(E + 3) / 4, 256, 0, stream>>>(
            X, Xb, sarr, node_idx, off, outZ, outBeta, E);
}

// Round 6
// 57.127 us; speedup vs baseline: 5.7327x; 1.0415x over previous
//
#include <hip/hip_runtime.h>
#include <hip/hip_bf16.h>
#include <math.h>

#define NEG_SLOPE 0.01f

typedef __attribute__((ext_vector_type(8))) short bf16x8;
typedef __attribute__((ext_vector_type(4))) float f32x4;

__device__ __forceinline__ float lrelu(float v) {
    return v > 0.0f ? v : NEG_SLOPE * v;
}

__device__ __forceinline__ short f2bf(float f) {
    __hip_bfloat16 h = __float2bfloat16(f);
    return *reinterpret_cast<short*>(&h);
}

// ---------------------------------------------------------------------------
// Pre-arrange W1 (fp32 [k=128][j=128]) into bf16 MFMA B-fragments.
// ---------------------------------------------------------------------------
__global__ void k_prep_w1(const float* __restrict__ W1, short* __restrict__ w1f) {
    int t = blockIdx.x * blockDim.x + threadIdx.x;  // 0..2047
    if (t >= 2048) return;
    int lane = t & 63;
    int fc = t >> 6;                 // 0..31 = jt*4 + kc
    int jt = fc >> 2, kc = fc & 3;
    int col = lane & 15;
    int k0 = kc * 32 + (lane >> 4) * 8;
    short* dst = w1f + (size_t)t * 8;
#pragma unroll
    for (int e = 0; e < 8; ++e)
        dst[e] = f2bf(W1[(size_t)(k0 + e) * 128 + jt * 16 + col]);
}

// ---------------------------------------------------------------------------
// Node scores via MFMA + side-product bf16 copy of X (row-major [N][128]).
// ---------------------------------------------------------------------------
__global__ void __launch_bounds__(256) k_node_score_mfma(
    const float* __restrict__ X, const short* __restrict__ w1f,
    const float* __restrict__ b1, const float* __restrict__ W2,
    const float* __restrict__ b2, float* __restrict__ sarr,
    unsigned short* __restrict__ Xb, int N) {
    __shared__ short w1s[32 * 64 * 8];  // 32 KB

    int tid = threadIdx.x;
    {
        const float4* src = (const float4*)w1f;
        float4* dst = (float4*)w1s;
#pragma unroll
        for (int i = 0; i < 8; ++i) dst[tid + 256 * i] = src[tid + 256 * i];
    }
    __syncthreads();

    int wid = tid >> 6, lane = tid & 63;
    int c15 = lane & 15, g = lane >> 4;
    int n0 = blockIdx.x * 64 + wid * 16;

    int arow = n0 + c15;
    size_t srow = (size_t)(arow < N ? arow : N - 1);
    const float* xr = X + srow * 128 + g * 8;
    bf16x8 afr[4];
#pragma unroll
    for (int kc = 0; kc < 4; ++kc) {
        float4 f0 = *(const float4*)(xr + kc * 32);
        float4 f1 = *(const float4*)(xr + kc * 32 + 4);
        bf16x8 a;
        a[0] = f2bf(f0.x); a[1] = f2bf(f0.y); a[2] = f2bf(f0.z); a[3] = f2bf(f0.w);
        a[4] = f2bf(f1.x); a[5] = f2bf(f1.y); a[6] = f2bf(f1.z); a[7] = f2bf(f1.w);
        afr[kc] = a;
        if (Xb)
            *(bf16x8*)(Xb + srow * 128 + kc * 32 + g * 8) = a;
    }

    float b1v[8], w2v[8];
#pragma unroll
    for (int jt = 0; jt < 8; ++jt) {
        b1v[jt] = b1[jt * 16 + c15];
        w2v[jt] = W2[jt * 16 + c15];
    }

    float sv[4] = {0.f, 0.f, 0.f, 0.f};
#pragma unroll
    for (int jt = 0; jt < 8; ++jt) {
        f32x4 acc = {0.f, 0.f, 0.f, 0.f};
#pragma unroll
        for (int kc = 0; kc < 4; ++kc) {
            bf16x8 bfr = *(const bf16x8*)(w1s + ((jt * 4 + kc) * 64 + lane) * 8);
            acc = __builtin_amdgcn_mfma_f32_16x16x32_bf16(afr[kc], bfr, acc, 0, 0, 0);
        }
#pragma unroll
        for (int i = 0; i < 4; ++i) {
            float h = acc[i] + b1v[jt];
            h = h > 0.f ? h : NEG_SLOPE * h;
            sv[i] += h * w2v[jt];
        }
    }

#pragma unroll
    for (int d = 1; d < 16; d <<= 1) {
#pragma unroll
        for (int i = 0; i < 4; ++i) sv[i] += __shfl_xor(sv[i], d, 64);
    }
    if (c15 == 0) {
        float bb = b2[0];
#pragma unroll
        for (int i = 0; i < 4; ++i) {
            int node = n0 + g * 4 + i;
            if (node < N) sarr[node] = sv[i] + bb;
        }
    }
}

// ---------------------------------------------------------------------------
// Per-edge member-range offsets from sorted edge_ids. off has E+1 entries.
// ---------------------------------------------------------------------------
__global__ void k_edge_offsets(const int* __restrict__ edge_ids,
                               int* __restrict__ off, int M, int E) {
    int m = blockIdx.x * blockDim.x + threadIdx.x;
    if (m >= M) return;
    int e = edge_ids[m];
    if (m == 0) {
        for (int q = 0; q <= e; ++q) off[q] = 0;
    } else {
        int p = edge_ids[m - 1];
        for (int q = p + 1; q <= e; ++q) off[q] = m;
    }
    if (m == M - 1) {
        for (int q = e + 1; q <= E; ++q) off[q] = M;
    }
}

// ---------------------------------------------------------------------------
// 8-rows-per-iteration weighted accumulate: two independent row gathers in
// flight per wave (rows t+g and t+4+g), 16 lanes per row, 8 cols per lane.
// prw is zero-padded (beta=0, idx=0) so the loop is branch-free.
// ---------------------------------------------------------------------------
template <int BF>
__device__ __forceinline__ void row8_acc(const float2* __restrict__ prw, int t,
                                         int g, int c,
                                         const unsigned short* __restrict__ Xb,
                                         const float* __restrict__ X,
                                         float* __restrict__ acc) {
    float2 pa = prw[t + g];
    float2 pb = prw[t + 4 + g];
    int ia = __float_as_int(pa.y);
    int ib = __float_as_int(pb.y);
    if (BF) {
        uint4 va = ((const uint4*)(Xb + (size_t)ia * 128))[c];
        uint4 vb = ((const uint4*)(Xb + (size_t)ib * 128))[c];
        float ba = pa.x, bb = pb.x;
        acc[0] += ba * __uint_as_float(va.x << 16);
        acc[1] += ba * __uint_as_float(va.x & 0xffff0000u);
        acc[2] += ba * __uint_as_float(va.y << 16);
        acc[3] += ba * __uint_as_float(va.y & 0xffff0000u);
        acc[4] += ba * __uint_as_float(va.z << 16);
        acc[5] += ba * __uint_as_float(va.z & 0xffff0000u);
        acc[6] += ba * __uint_as_float(va.w << 16);
        acc[7] += ba * __uint_as_float(va.w & 0xffff0000u);
        acc[0] += bb * __uint_as_float(vb.x << 16);
        acc[1] += bb * __uint_as_float(vb.x & 0xffff0000u);
        acc[2] += bb * __uint_as_float(vb.y << 16);
        acc[3] += bb * __uint_as_float(vb.y & 0xffff0000u);
        acc[4] += bb * __uint_as_float(vb.z << 16);
        acc[5] += bb * __uint_as_float(vb.z & 0xffff0000u);
        acc[6] += bb * __uint_as_float(vb.w << 16);
        acc[7] += bb * __uint_as_float(vb.w & 0xffff0000u);
    } else {
        const float4* xa = (const float4*)(X + (size_t)ia * 128 + c * 8);
        const float4* xb = (const float4*)(X + (size_t)ib * 128 + c * 8);
        float4 a0 = xa[0], a1 = xa[1];
        float4 b0 = xb[0], b1 = xb[1];
        float ba = pa.x, bb = pb.x;
        acc[0] += ba * a0.x; acc[1] += ba * a0.y;
        acc[2] += ba * a0.z; acc[3] += ba * a0.w;
        acc[4] += ba * a1.x; acc[5] += ba * a1.y;
        acc[6] += ba * a1.z; acc[7] += ba * a1.w;
        acc[0] += bb * b0.x; acc[1] += bb * b0.y;
        acc[2] += bb * b0.z; acc[3] += bb * b0.w;
        acc[4] += bb * b1.x; acc[5] += bb * b1.y;
        acc[6] += bb * b1.z; acc[7] += bb * b1.w;
    }
}

// ---------------------------------------------------------------------------
// One wave per edge, 4 edges per block. Fast path (n<=64): one sarr gather,
// one expf, butterfly softmax, zero barriers, branch-free 8-row inner loop.
// ---------------------------------------------------------------------------
template <int BF>
__global__ void __launch_bounds__(256) k_edge_agg(
    const float* __restrict__ X, const unsigned short* __restrict__ Xb,
    const float* __restrict__ sarr, const int* __restrict__ node_idx,
    const int* __restrict__ off, float* __restrict__ outZ,
    float* __restrict__ outBeta, int E) {
    int wid = threadIdx.x >> 6, lane = threadIdx.x & 63;
    int e = blockIdx.x * 4 + wid;
    if (e >= E) return;

    __shared__ float2 prs[4][64];   // {beta, bitcast(idx)} per member slot
    float2* prw = prs[wid];

    int s0 = off[e], n = off[e + 1] - s0;
    int g = lane >> 4, c = lane & 15;
    float acc[8] = {0.f, 0.f, 0.f, 0.f, 0.f, 0.f, 0.f, 0.f};

    if (n <= 64) {
        int idxv = 0;
        float svv = -INFINITY;
        if (lane < n) {
            idxv = node_idx[s0 + lane];
            svv = sarr[idxv];
        }
        float m = svv;
#pragma unroll
        for (int d = 1; d < 64; d <<= 1) m = fmaxf(m, __shfl_xor(m, d, 64));
        float ex = (lane < n) ? expf(svv - m) : 0.f;
        float sum = ex;
#pragma unroll
        for (int d = 1; d < 64; d <<= 1) sum += __shfl_xor(sum, d, 64);
        float inv = (n > 0) ? 1.f / sum : 0.f;
        float beta = ex * inv;
        if (lane < n) outBeta[s0 + lane] = beta;
        prw[lane] = make_float2(lane < n ? beta : 0.f,
                                __int_as_float(lane < n ? idxv : 0));
        int nr = (n + 7) & ~7;
        for (int t = 0; t < nr; t += 8)
            row8_acc<BF>(prw, t, g, c, Xb, X, acc);
    } else {
        // rare big-edge fallback (correctness path)
        float m = -INFINITY;
        for (int i = lane; i < n; i += 64)
            m = fmaxf(m, sarr[node_idx[s0 + i]]);
#pragma unroll
        for (int d = 1; d < 64; d <<= 1) m = fmaxf(m, __shfl_xor(m, d, 64));
        float sum = 0.f;
        for (int i = lane; i < n; i += 64)
            sum += expf(sarr[node_idx[s0 + i]] - m);
#pragma unroll
        for (int d = 1; d < 64; d <<= 1) sum += __shfl_xor(sum, d, 64);
        float inv = 1.f / sum;
        for (int base = 0; base < n; base += 64) {
            int cnt = min(64, n - base);
            int idxv = 0;
            float beta = 0.f;
            if (lane < cnt) {
                idxv = node_idx[s0 + base + lane];
                beta = expf(sarr[idxv] - m) * inv;
                outBeta[s0 + base + lane] = beta;
            }
            prw[lane] = make_float2(beta, __int_as_float(idxv));
            int cr = (cnt + 7) & ~7;
            for (int t = 0; t < cr; t += 8)
                row8_acc<BF>(prw, t, g, c, Xb, X, acc);
        }
    }

#pragma unroll
    for (int i = 0; i < 8; ++i) {
        acc[i] += __shfl_xor(acc[i], 16, 64);
        acc[i] += __shfl_xor(acc[i], 32, 64);
    }
    // all 64 lanes: each computes 2 of the 128 outputs (compile-time selects
    // avoid runtime-indexed-array scratch)
    float a0 = acc[0], a1 = acc[1];
    if (g == 1) { a0 = acc[2]; a1 = acc[3]; }
    else if (g == 2) { a0 = acc[4]; a1 = acc[5]; }
    else if (g == 3) { a0 = acc[6]; a1 = acc[7]; }
    float2 o;
    o.x = tanhf(lrelu(a0));
    o.y = tanhf(lrelu(a1));
    *(float2*)(outZ + (size_t)e * 128 + c * 8 + 2 * g) = o;
}

extern "C" void kernel_launch(void* const* d_in, const int* in_sizes, int n_in,
                              void* d_out, int out_size, void* d_ws, size_t ws_size,
                              hipStream_t stream) {
    const float* X  = (const float*)d_in[0];
    const float* W1 = (const float*)d_in[1];
    const float* b1 = (const float*)d_in[2];
    const float* W2 = (const float*)d_in[3];
    const float* b2 = (const float*)d_in[4];
    const int* node_idx = (const int*)d_in[5];
    const int* edge_ids = (const int*)d_in[6];

    int N = in_sizes[0] / 128;          // 100000 nodes
    int M = in_sizes[5];                // 640000 memberships
    int E = (out_size - M) / 128;       // 20000 hyperedges

    // workspace: w1f 32KB | sarr N f32 | off E+1 ints | Xb N*128 bf16
    char* p = (char*)d_ws;
    short* w1f  = (short*)p;
    float* sarr = (float*)(p + 32768);
    int*   off  = (int*)(p + 32768 + (size_t)N * 4);
    size_t xb_off = (32768 + (size_t)N * 4 + (size_t)(E + 1) * 4 + 255) & ~(size_t)255;
    unsigned short* Xb = (unsigned short*)(p + xb_off);
    bool useBF = ws_size >= xb_off + (size_t)N * 128 * 2;

    float* outZ    = (float*)d_out;
    float* outBeta = outZ + (size_t)E * 128;

    k_prep_w1<<<8, 256, 0, stream>>>(W1, w1f);
    k_node_score_mfma<<<(N + 63) / 64, 256, 0, stream>>>(
        X, w1f, b1, W2, b2, sarr, useBF ? Xb : (unsigned short*)nullptr, N);
    k_edge_offsets<<<(M + 255) / 256, 256, 0, stream>>>(edge_ids, off, M, E);
    if (useBF)
        k_edge_agg<1><<<(E + 3) / 4, 256, 0, stream>>>(
            X, Xb, sarr, node_idx, off, outZ, outBeta, E);
    else
        k_edge_agg<0><<<(E + 3) / 4, 256, 0, stream>>>(
            X, Xb, sarr, node_idx, off, outZ, outBeta, E);
}

// Round 7
// 53.844 us; speedup vs baseline: 6.0822x; 1.0610x over previous
//
#include <hip/hip_runtime.h>
#include <hip/hip_bf16.h>
#include <math.h>

#define NEG_SLOPE 0.01f

typedef __attribute__((ext_vector_type(8))) short bf16x8;
typedef __attribute__((ext_vector_type(4))) float f32x4;

__device__ __forceinline__ float lrelu(float v) {
    return v > 0.0f ? v : NEG_SLOPE * v;
}

__device__ __forceinline__ short f2bf(float f) {
    __hip_bfloat16 h = __float2bfloat16(f);
    return *reinterpret_cast<short*>(&h);
}

// ---------------------------------------------------------------------------
// Fused prelude: blocks 0..7 pre-arrange W1 into bf16 MFMA B-fragments;
// remaining blocks compute per-edge member-range offsets from sorted edge_ids.
// ---------------------------------------------------------------------------
__global__ void k_prep_and_offsets(const float* __restrict__ W1,
                                   short* __restrict__ w1f,
                                   const int* __restrict__ edge_ids,
                                   int* __restrict__ off, int M, int E) {
    int b = blockIdx.x;
    if (b < 8) {
        int t = b * 256 + threadIdx.x;  // 0..2047
        int lane = t & 63;
        int fc = t >> 6;                 // 0..31 = jt*4 + kc
        int jt = fc >> 2, kc = fc & 3;
        int col = lane & 15;
        int k0 = kc * 32 + (lane >> 4) * 8;
        short* dst = w1f + (size_t)t * 8;
#pragma unroll
        for (int e = 0; e < 8; ++e)
            dst[e] = f2bf(W1[(size_t)(k0 + e) * 128 + jt * 16 + col]);
    } else {
        int m = (b - 8) * 256 + threadIdx.x;
        if (m >= M) return;
        int e = edge_ids[m];
        if (m == 0) {
            for (int q = 0; q <= e; ++q) off[q] = 0;
        } else {
            int p = edge_ids[m - 1];
            for (int q = p + 1; q <= e; ++q) off[q] = m;
        }
        if (m == M - 1) {
            for (int q = e + 1; q <= E; ++q) off[q] = M;
        }
    }
}

// ---------------------------------------------------------------------------
// Node scores via MFMA + side-product bf16 copy of X (row-major [N][128]).
// ---------------------------------------------------------------------------
__global__ void __launch_bounds__(256) k_node_score_mfma(
    const float* __restrict__ X, const short* __restrict__ w1f,
    const float* __restrict__ b1, const float* __restrict__ W2,
    const float* __restrict__ b2, float* __restrict__ sarr,
    unsigned short* __restrict__ Xb, int N) {
    __shared__ short w1s[32 * 64 * 8];  // 32 KB

    int tid = threadIdx.x;
    {
        const float4* src = (const float4*)w1f;
        float4* dst = (float4*)w1s;
#pragma unroll
        for (int i = 0; i < 8; ++i) dst[tid + 256 * i] = src[tid + 256 * i];
    }
    __syncthreads();

    int wid = tid >> 6, lane = tid & 63;
    int c15 = lane & 15, g = lane >> 4;
    int n0 = blockIdx.x * 64 + wid * 16;

    int arow = n0 + c15;
    size_t srow = (size_t)(arow < N ? arow : N - 1);
    const float* xr = X + srow * 128 + g * 8;
    bf16x8 afr[4];
#pragma unroll
    for (int kc = 0; kc < 4; ++kc) {
        float4 f0 = *(const float4*)(xr + kc * 32);
        float4 f1 = *(const float4*)(xr + kc * 32 + 4);
        bf16x8 a;
        a[0] = f2bf(f0.x); a[1] = f2bf(f0.y); a[2] = f2bf(f0.z); a[3] = f2bf(f0.w);
        a[4] = f2bf(f1.x); a[5] = f2bf(f1.y); a[6] = f2bf(f1.z); a[7] = f2bf(f1.w);
        afr[kc] = a;
        if (Xb)
            *(bf16x8*)(Xb + srow * 128 + kc * 32 + g * 8) = a;
    }

    float b1v[8], w2v[8];
#pragma unroll
    for (int jt = 0; jt < 8; ++jt) {
        b1v[jt] = b1[jt * 16 + c15];
        w2v[jt] = W2[jt * 16 + c15];
    }

    float sv[4] = {0.f, 0.f, 0.f, 0.f};
#pragma unroll
    for (int jt = 0; jt < 8; ++jt) {
        f32x4 acc = {0.f, 0.f, 0.f, 0.f};
#pragma unroll
        for (int kc = 0; kc < 4; ++kc) {
            bf16x8 bfr = *(const bf16x8*)(w1s + ((jt * 4 + kc) * 64 + lane) * 8);
            acc = __builtin_amdgcn_mfma_f32_16x16x32_bf16(afr[kc], bfr, acc, 0, 0, 0);
        }
#pragma unroll
        for (int i = 0; i < 4; ++i) {
            float h = acc[i] + b1v[jt];
            h = h > 0.f ? h : NEG_SLOPE * h;
            sv[i] += h * w2v[jt];
        }
    }

#pragma unroll
    for (int d = 1; d < 16; d <<= 1) {
#pragma unroll
        for (int i = 0; i < 4; ++i) sv[i] += __shfl_xor(sv[i], d, 64);
    }
    if (c15 == 0) {
        float bb = b2[0];
#pragma unroll
        for (int i = 0; i < 4; ++i) {
            int node = n0 + g * 4 + i;
            if (node < N) sarr[node] = sv[i] + bb;
        }
    }
}

// ---------------------------------------------------------------------------
// 16-rows-per-iteration weighted accumulate: FOUR independent row gathers in
// flight per wave (rows t+g, t+4+g, t+8+g, t+12+g), 16 lanes per row,
// 8 cols per lane. prw is zero-padded (beta=0, idx=0) so loop is branch-free.
// ---------------------------------------------------------------------------
template <int BF>
__device__ __forceinline__ void row16_acc(const float2* __restrict__ prw, int t,
                                          int g, int c,
                                          const unsigned short* __restrict__ Xb,
                                          const float* __restrict__ X,
                                          float* __restrict__ acc) {
    float2 p0 = prw[t + g];
    float2 p1 = prw[t + 4 + g];
    float2 p2 = prw[t + 8 + g];
    float2 p3 = prw[t + 12 + g];
    int i0 = __float_as_int(p0.y);
    int i1 = __float_as_int(p1.y);
    int i2 = __float_as_int(p2.y);
    int i3 = __float_as_int(p3.y);
    if (BF) {
        uint4 v0 = ((const uint4*)(Xb + (size_t)i0 * 128))[c];
        uint4 v1 = ((const uint4*)(Xb + (size_t)i1 * 128))[c];
        uint4 v2 = ((const uint4*)(Xb + (size_t)i2 * 128))[c];
        uint4 v3 = ((const uint4*)(Xb + (size_t)i3 * 128))[c];
        float b0 = p0.x, b1_ = p1.x, b2_ = p2.x, b3 = p3.x;
        acc[0] += b0 * __uint_as_float(v0.x << 16);
        acc[1] += b0 * __uint_as_float(v0.x & 0xffff0000u);
        acc[2] += b0 * __uint_as_float(v0.y << 16);
        acc[3] += b0 * __uint_as_float(v0.y & 0xffff0000u);
        acc[4] += b0 * __uint_as_float(v0.z << 16);
        acc[5] += b0 * __uint_as_float(v0.z & 0xffff0000u);
        acc[6] += b0 * __uint_as_float(v0.w << 16);
        acc[7] += b0 * __uint_as_float(v0.w & 0xffff0000u);
        acc[0] += b1_ * __uint_as_float(v1.x << 16);
        acc[1] += b1_ * __uint_as_float(v1.x & 0xffff0000u);
        acc[2] += b1_ * __uint_as_float(v1.y << 16);
        acc[3] += b1_ * __uint_as_float(v1.y & 0xffff0000u);
        acc[4] += b1_ * __uint_as_float(v1.z << 16);
        acc[5] += b1_ * __uint_as_float(v1.z & 0xffff0000u);
        acc[6] += b1_ * __uint_as_float(v1.w << 16);
        acc[7] += b1_ * __uint_as_float(v1.w & 0xffff0000u);
        acc[0] += b2_ * __uint_as_float(v2.x << 16);
        acc[1] += b2_ * __uint_as_float(v2.x & 0xffff0000u);
        acc[2] += b2_ * __uint_as_float(v2.y << 16);
        acc[3] += b2_ * __uint_as_float(v2.y & 0xffff0000u);
        acc[4] += b2_ * __uint_as_float(v2.z << 16);
        acc[5] += b2_ * __uint_as_float(v2.z & 0xffff0000u);
        acc[6] += b2_ * __uint_as_float(v2.w << 16);
        acc[7] += b2_ * __uint_as_float(v2.w & 0xffff0000u);
        acc[0] += b3 * __uint_as_float(v3.x << 16);
        acc[1] += b3 * __uint_as_float(v3.x & 0xffff0000u);
        acc[2] += b3 * __uint_as_float(v3.y << 16);
        acc[3] += b3 * __uint_as_float(v3.y & 0xffff0000u);
        acc[4] += b3 * __uint_as_float(v3.z << 16);
        acc[5] += b3 * __uint_as_float(v3.z & 0xffff0000u);
        acc[6] += b3 * __uint_as_float(v3.w << 16);
        acc[7] += b3 * __uint_as_float(v3.w & 0xffff0000u);
    } else {
        const float4* xa = (const float4*)(X + (size_t)i0 * 128 + c * 8);
        const float4* xb = (const float4*)(X + (size_t)i1 * 128 + c * 8);
        const float4* xc = (const float4*)(X + (size_t)i2 * 128 + c * 8);
        const float4* xd = (const float4*)(X + (size_t)i3 * 128 + c * 8);
        float4 a0 = xa[0], a1 = xa[1];
        float4 b0 = xb[0], b1v = xb[1];
        float4 c0 = xc[0], c1 = xc[1];
        float4 d0 = xd[0], d1 = xd[1];
        acc[0] += p0.x * a0.x; acc[1] += p0.x * a0.y;
        acc[2] += p0.x * a0.z; acc[3] += p0.x * a0.w;
        acc[4] += p0.x * a1.x; acc[5] += p0.x * a1.y;
        acc[6] += p0.x * a1.z; acc[7] += p0.x * a1.w;
        acc[0] += p1.x * b0.x; acc[1] += p1.x * b0.y;
        acc[2] += p1.x * b0.z; acc[3] += p1.x * b0.w;
        acc[4] += p1.x * b1v.x; acc[5] += p1.x * b1v.y;
        acc[6] += p1.x * b1v.z; acc[7] += p1.x * b1v.w;
        acc[0] += p2.x * c0.x; acc[1] += p2.x * c0.y;
        acc[2] += p2.x * c0.z; acc[3] += p2.x * c0.w;
        acc[4] += p2.x * c1.x; acc[5] += p2.x * c1.y;
        acc[6] += p2.x * c1.z; acc[7] += p2.x * c1.w;
        acc[0] += p3.x * d0.x; acc[1] += p3.x * d0.y;
        acc[2] += p3.x * d0.z; acc[3] += p3.x * d0.w;
        acc[4] += p3.x * d1.x; acc[5] += p3.x * d1.y;
        acc[6] += p3.x * d1.z; acc[7] += p3.x * d1.w;
    }
}

// ---------------------------------------------------------------------------
// One wave per edge, 4 edges per block. Fast path (n<=64): one sarr gather,
// one expf, butterfly softmax, zero barriers, branch-free 16-row inner loop.
// ---------------------------------------------------------------------------
template <int BF>
__global__ void __launch_bounds__(256) k_edge_agg(
    const float* __restrict__ X, const unsigned short* __restrict__ Xb,
    const float* __restrict__ sarr, const int* __restrict__ node_idx,
    const int* __restrict__ off, float* __restrict__ outZ,
    float* __restrict__ outBeta, int E) {
    int wid = threadIdx.x >> 6, lane = threadIdx.x & 63;
    int e = blockIdx.x * 4 + wid;
    if (e >= E) return;

    __shared__ float2 prs[4][64];   // {beta, bitcast(idx)} per member slot
    float2* prw = prs[wid];

    int s0 = off[e], n = off[e + 1] - s0;
    int g = lane >> 4, c = lane & 15;
    float acc[8] = {0.f, 0.f, 0.f, 0.f, 0.f, 0.f, 0.f, 0.f};

    if (n <= 64) {
        int idxv = 0;
        float svv = -INFINITY;
        if (lane < n) {
            idxv = node_idx[s0 + lane];
            svv = sarr[idxv];
        }
        float m = svv;
#pragma unroll
        for (int d = 1; d < 64; d <<= 1) m = fmaxf(m, __shfl_xor(m, d, 64));
        float ex = (lane < n) ? expf(svv - m) : 0.f;
        float sum = ex;
#pragma unroll
        for (int d = 1; d < 64; d <<= 1) sum += __shfl_xor(sum, d, 64);
        float inv = (n > 0) ? 1.f / sum : 0.f;
        float beta = ex * inv;
        if (lane < n) outBeta[s0 + lane] = beta;
        prw[lane] = make_float2(lane < n ? beta : 0.f,
                                __int_as_float(lane < n ? idxv : 0));
        int nr = (n + 15) & ~15;
        for (int t = 0; t < nr; t += 16)
            row16_acc<BF>(prw, t, g, c, Xb, X, acc);
    } else {
        // rare big-edge fallback (correctness path)
        float m = -INFINITY;
        for (int i = lane; i < n; i += 64)
            m = fmaxf(m, sarr[node_idx[s0 + i]]);
#pragma unroll
        for (int d = 1; d < 64; d <<= 1) m = fmaxf(m, __shfl_xor(m, d, 64));
        float sum = 0.f;
        for (int i = lane; i < n; i += 64)
            sum += expf(sarr[node_idx[s0 + i]] - m);
#pragma unroll
        for (int d = 1; d < 64; d <<= 1) sum += __shfl_xor(sum, d, 64);
        float inv = 1.f / sum;
        for (int base = 0; base < n; base += 64) {
            int cnt = min(64, n - base);
            int idxv = 0;
            float beta = 0.f;
            if (lane < cnt) {
                idxv = node_idx[s0 + base + lane];
                beta = expf(sarr[idxv] - m) * inv;
                outBeta[s0 + base + lane] = beta;
            }
            prw[lane] = make_float2(beta, __int_as_float(idxv));
            int cr = (cnt + 15) & ~15;
            for (int t = 0; t < cr; t += 16)
                row16_acc<BF>(prw, t, g, c, Xb, X, acc);
        }
    }

#pragma unroll
    for (int i = 0; i < 8; ++i) {
        acc[i] += __shfl_xor(acc[i], 16, 64);
        acc[i] += __shfl_xor(acc[i], 32, 64);
    }
    // all 64 lanes: each computes 2 of the 128 outputs (compile-time selects
    // avoid runtime-indexed-array scratch)
    float a0 = acc[0], a1 = acc[1];
    if (g == 1) { a0 = acc[2]; a1 = acc[3]; }
    else if (g == 2) { a0 = acc[4]; a1 = acc[5]; }
    else if (g == 3) { a0 = acc[6]; a1 = acc[7]; }
    float2 o;
    o.x = tanhf(lrelu(a0));
    o.y = tanhf(lrelu(a1));
    *(float2*)(outZ + (size_t)e * 128 + c * 8 + 2 * g) = o;
}

extern "C" void kernel_launch(void* const* d_in, const int* in_sizes, int n_in,
                              void* d_out, int out_size, void* d_ws, size_t ws_size,
                              hipStream_t stream) {
    const float* X  = (const float*)d_in[0];
    const float* W1 = (const float*)d_in[1];
    const float* b1 = (const float*)d_in[2];
    const float* W2 = (const float*)d_in[3];
    const float* b2 = (const float*)d_in[4];
    const int* node_idx = (const int*)d_in[5];
    const int* edge_ids = (const int*)d_in[6];

    int N = in_sizes[0] / 128;          // 100000 nodes
    int M = in_sizes[5];                // 640000 memberships
    int E = (out_size - M) / 128;       // 20000 hyperedges

    // workspace: w1f 32KB | sarr N f32 | off E+1 ints | Xb N*128 bf16
    char* p = (char*)d_ws;
    short* w1f  = (short*)p;
    float* sarr = (float*)(p + 32768);
    int*   off  = (int*)(p + 32768 + (size_t)N * 4);
    size_t xb_off = (32768 + (size_t)N * 4 + (size_t)(E + 1) * 4 + 255) & ~(size_t)255;
    unsigned short* Xb = (unsigned short*)(p + xb_off);
    bool useBF = ws_size >= xb_off + (size_t)N * 128 * 2;

    float* outZ    = (float*)d_out;
    float* outBeta = outZ + (size_t)E * 128;

    k_prep_and_offsets<<<8 + (M + 255) / 256, 256, 0, stream>>>(
        W1, w1f, edge_ids, off, M, E);
    k_node_score_mfma<<<(N + 63) / 64, 256, 0, stream>>>(
        X, w1f, b1, W2, b2, sarr, useBF ? Xb : (unsigned short*)nullptr, N);
    if (useBF)
        k_edge_agg<1><<<(E + 3) / 4, 256, 0, stream>>>(
            X, Xb, sarr, node_idx, off, outZ, outBeta, E);
    else
        k_edge_agg<0><<<(E + 3) / 4, 256, 0, stream>>>(
            X, Xb, sarr, node_idx, off, outZ, outBeta, E);
}

// Round 8
// 50.550 us; speedup vs baseline: 6.4785x; 1.0652x over previous
//
#include <hip/hip_runtime.h>
#include <hip/hip_bf16.h>
#include <math.h>

#define NEG_SLOPE 0.01f

typedef __attribute__((ext_vector_type(8))) short bf16x8;
typedef __attribute__((ext_vector_type(4))) float f32x4;

__device__ __forceinline__ float lrelu(float v) {
    return v > 0.0f ? v : NEG_SLOPE * v;
}

__device__ __forceinline__ short f2bf(float f) {
    __hip_bfloat16 h = __float2bfloat16(f);
    return *reinterpret_cast<short*>(&h);
}

// ---------------------------------------------------------------------------
// Fused kernel 1.
// Blocks [0, SB): node scores via MFMA + bf16 X copy. W1 frags are built
//   in-block from W1 directly (64 KB L2-broadcast; no prep dependency).
// Blocks [SB, SB+OB): per-edge member offsets from sorted edge_ids.
// ---------------------------------------------------------------------------
__global__ void __launch_bounds__(256) k_score_and_offsets(
    const float* __restrict__ X, const float* __restrict__ W1,
    const float* __restrict__ b1, const float* __restrict__ W2,
    const float* __restrict__ b2, float* __restrict__ sarr,
    unsigned short* __restrict__ Xb, int N, int SB,
    const int* __restrict__ edge_ids, int* __restrict__ off, int M, int E) {
    __shared__ short w1s[32 * 64 * 8];  // 32 KB frag image of W1

    int b = blockIdx.x;
    int tid = threadIdx.x;

    if (b >= SB) {
        // ---- offsets path (no LDS use) ----
        int m = (b - SB) * 256 + tid;
        if (m >= M) return;
        int e = edge_ids[m];
        if (m == 0) {
            for (int q = 0; q <= e; ++q) off[q] = 0;
        } else {
            int p = edge_ids[m - 1];
            for (int q = p + 1; q <= e; ++q) off[q] = m;
        }
        if (m == M - 1) {
            for (int q = e + 1; q <= E; ++q) off[q] = M;
        }
        return;
    }

    // ---- node-score path ----
    // stage W1 -> LDS in MFMA B-frag layout (frag fc=jt*4+kc, lane, elem e):
    // w1s[(fc*64+lane)*8+e] = bf16(W1[(kc*32+(lane>>4)*8+e)*128 + jt*16+(lane&15)])
#pragma unroll
    for (int it = 0; it < 8; ++it) {
        int t = it * 256 + tid;          // 0..2047 virtual prep thread
        int lane = t & 63;
        int fc = t >> 6;
        int jt = fc >> 2, kc = fc & 3;
        int col = lane & 15;
        int k0 = kc * 32 + ((lane >> 4) << 3);
        const float* wsrc = W1 + (size_t)k0 * 128 + jt * 16 + col;
        bf16x8 fr;
#pragma unroll
        for (int e = 0; e < 8; ++e) fr[e] = f2bf(wsrc[e * 128]);
        *(bf16x8*)(w1s + (size_t)t * 8) = fr;
    }
    __syncthreads();

    int wid = tid >> 6, lane = tid & 63;
    int c15 = lane & 15, g = lane >> 4;
    int n0 = b * 64 + wid * 16;

    int arow = n0 + c15;
    size_t srow = (size_t)(arow < N ? arow : N - 1);
    const float* xr = X + srow * 128 + g * 8;
    bf16x8 afr[4];
#pragma unroll
    for (int kc = 0; kc < 4; ++kc) {
        float4 f0 = *(const float4*)(xr + kc * 32);
        float4 f1 = *(const float4*)(xr + kc * 32 + 4);
        bf16x8 a;
        a[0] = f2bf(f0.x); a[1] = f2bf(f0.y); a[2] = f2bf(f0.z); a[3] = f2bf(f0.w);
        a[4] = f2bf(f1.x); a[5] = f2bf(f1.y); a[6] = f2bf(f1.z); a[7] = f2bf(f1.w);
        afr[kc] = a;
        if (Xb)
            *(bf16x8*)(Xb + srow * 128 + kc * 32 + g * 8) = a;
    }

    float b1v[8], w2v[8];
#pragma unroll
    for (int jt = 0; jt < 8; ++jt) {
        b1v[jt] = b1[jt * 16 + c15];
        w2v[jt] = W2[jt * 16 + c15];
    }

    float sv[4] = {0.f, 0.f, 0.f, 0.f};
#pragma unroll
    for (int jt = 0; jt < 8; ++jt) {
        f32x4 acc = {0.f, 0.f, 0.f, 0.f};
#pragma unroll
        for (int kc = 0; kc < 4; ++kc) {
            bf16x8 bfr = *(const bf16x8*)(w1s + ((jt * 4 + kc) * 64 + lane) * 8);
            acc = __builtin_amdgcn_mfma_f32_16x16x32_bf16(afr[kc], bfr, acc, 0, 0, 0);
        }
#pragma unroll
        for (int i = 0; i < 4; ++i) {
            float h = acc[i] + b1v[jt];
            h = h > 0.f ? h : NEG_SLOPE * h;
            sv[i] += h * w2v[jt];
        }
    }

#pragma unroll
    for (int d = 1; d < 16; d <<= 1) {
#pragma unroll
        for (int i = 0; i < 4; ++i) sv[i] += __shfl_xor(sv[i], d, 64);
    }
    if (c15 == 0) {
        float bb = b2[0];
#pragma unroll
        for (int i = 0; i < 4; ++i) {
            int node = n0 + g * 4 + i;
            if (node < N) sarr[node] = sv[i] + bb;
        }
    }
}

// ---------------------------------------------------------------------------
// 16-rows-per-iteration weighted accumulate: FOUR independent row gathers in
// flight per wave (rows t+g, t+4+g, t+8+g, t+12+g), 16 lanes per row,
// 8 cols per lane. prw is zero-padded (beta=0, idx=0) so loop is branch-free.
// ---------------------------------------------------------------------------
template <int BF>
__device__ __forceinline__ void row16_acc(const float2* __restrict__ prw, int t,
                                          int g, int c,
                                          const unsigned short* __restrict__ Xb,
                                          const float* __restrict__ X,
                                          float* __restrict__ acc) {
    float2 p0 = prw[t + g];
    float2 p1 = prw[t + 4 + g];
    float2 p2 = prw[t + 8 + g];
    float2 p3 = prw[t + 12 + g];
    int i0 = __float_as_int(p0.y);
    int i1 = __float_as_int(p1.y);
    int i2 = __float_as_int(p2.y);
    int i3 = __float_as_int(p3.y);
    if (BF) {
        uint4 v0 = ((const uint4*)(Xb + (size_t)i0 * 128))[c];
        uint4 v1 = ((const uint4*)(Xb + (size_t)i1 * 128))[c];
        uint4 v2 = ((const uint4*)(Xb + (size_t)i2 * 128))[c];
        uint4 v3 = ((const uint4*)(Xb + (size_t)i3 * 128))[c];
        float b0 = p0.x, b1_ = p1.x, b2_ = p2.x, b3 = p3.x;
        acc[0] += b0 * __uint_as_float(v0.x << 16);
        acc[1] += b0 * __uint_as_float(v0.x & 0xffff0000u);
        acc[2] += b0 * __uint_as_float(v0.y << 16);
        acc[3] += b0 * __uint_as_float(v0.y & 0xffff0000u);
        acc[4] += b0 * __uint_as_float(v0.z << 16);
        acc[5] += b0 * __uint_as_float(v0.z & 0xffff0000u);
        acc[6] += b0 * __uint_as_float(v0.w << 16);
        acc[7] += b0 * __uint_as_float(v0.w & 0xffff0000u);
        acc[0] += b1_ * __uint_as_float(v1.x << 16);
        acc[1] += b1_ * __uint_as_float(v1.x & 0xffff0000u);
        acc[2] += b1_ * __uint_as_float(v1.y << 16);
        acc[3] += b1_ * __uint_as_float(v1.y & 0xffff0000u);
        acc[4] += b1_ * __uint_as_float(v1.z << 16);
        acc[5] += b1_ * __uint_as_float(v1.z & 0xffff0000u);
        acc[6] += b1_ * __uint_as_float(v1.w << 16);
        acc[7] += b1_ * __uint_as_float(v1.w & 0xffff0000u);
        acc[0] += b2_ * __uint_as_float(v2.x << 16);
        acc[1] += b2_ * __uint_as_float(v2.x & 0xffff0000u);
        acc[2] += b2_ * __uint_as_float(v2.y << 16);
        acc[3] += b2_ * __uint_as_float(v2.y & 0xffff0000u);
        acc[4] += b2_ * __uint_as_float(v2.z << 16);
        acc[5] += b2_ * __uint_as_float(v2.z & 0xffff0000u);
        acc[6] += b2_ * __uint_as_float(v2.w << 16);
        acc[7] += b2_ * __uint_as_float(v2.w & 0xffff0000u);
        acc[0] += b3 * __uint_as_float(v3.x << 16);
        acc[1] += b3 * __uint_as_float(v3.x & 0xffff0000u);
        acc[2] += b3 * __uint_as_float(v3.y << 16);
        acc[3] += b3 * __uint_as_float(v3.y & 0xffff0000u);
        acc[4] += b3 * __uint_as_float(v3.z << 16);
        acc[5] += b3 * __uint_as_float(v3.z & 0xffff0000u);
        acc[6] += b3 * __uint_as_float(v3.w << 16);
        acc[7] += b3 * __uint_as_float(v3.w & 0xffff0000u);
    } else {
        const float4* xa = (const float4*)(X + (size_t)i0 * 128 + c * 8);
        const float4* xb = (const float4*)(X + (size_t)i1 * 128 + c * 8);
        const float4* xc = (const float4*)(X + (size_t)i2 * 128 + c * 8);
        const float4* xd = (const float4*)(X + (size_t)i3 * 128 + c * 8);
        float4 a0 = xa[0], a1 = xa[1];
        float4 b0 = xb[0], b1v = xb[1];
        float4 c0 = xc[0], c1 = xc[1];
        float4 d0 = xd[0], d1 = xd[1];
        acc[0] += p0.x * a0.x; acc[1] += p0.x * a0.y;
        acc[2] += p0.x * a0.z; acc[3] += p0.x * a0.w;
        acc[4] += p0.x * a1.x; acc[5] += p0.x * a1.y;
        acc[6] += p0.x * a1.z; acc[7] += p0.x * a1.w;
        acc[0] += p1.x * b0.x; acc[1] += p1.x * b0.y;
        acc[2] += p1.x * b0.z; acc[3] += p1.x * b0.w;
        acc[4] += p1.x * b1v.x; acc[5] += p1.x * b1v.y;
        acc[6] += p1.x * b1v.z; acc[7] += p1.x * b1v.w;
        acc[0] += p2.x * c0.x; acc[1] += p2.x * c0.y;
        acc[2] += p2.x * c0.z; acc[3] += p2.x * c0.w;
        acc[4] += p2.x * c1.x; acc[5] += p2.x * c1.y;
        acc[6] += p2.x * c1.z; acc[7] += p2.x * c1.w;
        acc[0] += p3.x * d0.x; acc[1] += p3.x * d0.y;
        acc[2] += p3.x * d0.z; acc[3] += p3.x * d0.w;
        acc[4] += p3.x * d1.x; acc[5] += p3.x * d1.y;
        acc[6] += p3.x * d1.z; acc[7] += p3.x * d1.w;
    }
}

// ---------------------------------------------------------------------------
// One wave per edge, 4 edges per block. Fast path (n<=64): one sarr gather,
// one expf, butterfly softmax, zero barriers, branch-free 16-row inner loop.
// ---------------------------------------------------------------------------
template <int BF>
__global__ void __launch_bounds__(256) k_edge_agg(
    const float* __restrict__ X, const unsigned short* __restrict__ Xb,
    const float* __restrict__ sarr, const int* __restrict__ node_idx,
    const int* __restrict__ off, float* __restrict__ outZ,
    float* __restrict__ outBeta, int E) {
    int wid = threadIdx.x >> 6, lane = threadIdx.x & 63;
    int e = blockIdx.x * 4 + wid;
    if (e >= E) return;

    __shared__ float2 prs[4][64];   // {beta, bitcast(idx)} per member slot
    float2* prw = prs[wid];

    int s0 = off[e], n = off[e + 1] - s0;
    int g = lane >> 4, c = lane & 15;
    float acc[8] = {0.f, 0.f, 0.f, 0.f, 0.f, 0.f, 0.f, 0.f};

    if (n <= 64) {
        int idxv = 0;
        float svv = -INFINITY;
        if (lane < n) {
            idxv = node_idx[s0 + lane];
            svv = sarr[idxv];
        }
        float m = svv;
#pragma unroll
        for (int d = 1; d < 64; d <<= 1) m = fmaxf(m, __shfl_xor(m, d, 64));
        float ex = (lane < n) ? expf(svv - m) : 0.f;
        float sum = ex;
#pragma unroll
        for (int d = 1; d < 64; d <<= 1) sum += __shfl_xor(sum, d, 64);
        float inv = (n > 0) ? 1.f / sum : 0.f;
        float beta = ex * inv;
        if (lane < n) outBeta[s0 + lane] = beta;
        prw[lane] = make_float2(lane < n ? beta : 0.f,
                                __int_as_float(lane < n ? idxv : 0));
        int nr = (n + 15) & ~15;
        for (int t = 0; t < nr; t += 16)
            row16_acc<BF>(prw, t, g, c, Xb, X, acc);
    } else {
        // rare big-edge fallback (correctness path)
        float m = -INFINITY;
        for (int i = lane; i < n; i += 64)
            m = fmaxf(m, sarr[node_idx[s0 + i]]);
#pragma unroll
        for (int d = 1; d < 64; d <<= 1) m = fmaxf(m, __shfl_xor(m, d, 64));
        float sum = 0.f;
        for (int i = lane; i < n; i += 64)
            sum += expf(sarr[node_idx[s0 + i]] - m);
#pragma unroll
        for (int d = 1; d < 64; d <<= 1) sum += __shfl_xor(sum, d, 64);
        float inv = 1.f / sum;
        for (int base = 0; base < n; base += 64) {
            int cnt = min(64, n - base);
            int idxv = 0;
            float beta = 0.f;
            if (lane < cnt) {
                idxv = node_idx[s0 + base + lane];
                beta = expf(sarr[idxv] - m) * inv;
                outBeta[s0 + base + lane] = beta;
            }
            prw[lane] = make_float2(beta, __int_as_float(idxv));
            int cr = (cnt + 15) & ~15;
            for (int t = 0; t < cr; t += 16)
                row16_acc<BF>(prw, t, g, c, Xb, X, acc);
        }
    }

#pragma unroll
    for (int i = 0; i < 8; ++i) {
        acc[i] += __shfl_xor(acc[i], 16, 64);
        acc[i] += __shfl_xor(acc[i], 32, 64);
    }
    // all 64 lanes: each computes 2 of the 128 outputs (compile-time selects
    // avoid runtime-indexed-array scratch)
    float a0 = acc[0], a1 = acc[1];
    if (g == 1) { a0 = acc[2]; a1 = acc[3]; }
    else if (g == 2) { a0 = acc[4]; a1 = acc[5]; }
    else if (g == 3) { a0 = acc[6]; a1 = acc[7]; }
    float2 o;
    o.x = tanhf(lrelu(a0));
    o.y = tanhf(lrelu(a1));
    *(float2*)(outZ + (size_t)e * 128 + c * 8 + 2 * g) = o;
}

extern "C" void kernel_launch(void* const* d_in, const int* in_sizes, int n_in,
                              void* d_out, int out_size, void* d_ws, size_t ws_size,
                              hipStream_t stream) {
    const float* X  = (const float*)d_in[0];
    const float* W1 = (const float*)d_in[1];
    const float* b1 = (const float*)d_in[2];
    const float* W2 = (const float*)d_in[3];
    const float* b2 = (const float*)d_in[4];
    const int* node_idx = (const int*)d_in[5];
    const int* edge_ids = (const int*)d_in[6];

    int N = in_sizes[0] / 128;          // 100000 nodes
    int M = in_sizes[5];                // 640000 memberships
    int E = (out_size - M) / 128;       // 20000 hyperedges

    // workspace: sarr N f32 | off E+1 ints | Xb N*128 bf16
    char* p = (char*)d_ws;
    float* sarr = (float*)p;
    int*   off  = (int*)(p + (size_t)N * 4);
    size_t xb_off = ((size_t)N * 4 + (size_t)(E + 1) * 4 + 255) & ~(size_t)255;
    unsigned short* Xb = (unsigned short*)(p + xb_off);
    bool useBF = ws_size >= xb_off + (size_t)N * 128 * 2;

    float* outZ    = (float*)d_out;
    float* outBeta = outZ + (size_t)E * 128;

    int SB = (N + 63) / 64;             // node-score blocks (first in grid)
    int OB = (M + 255) / 256;           // offsets blocks
    k_score_and_offsets<<<SB + OB, 256, 0, stream>>>(
        X, W1, b1, W2, b2, sarr, useBF ? Xb : (unsigned short*)nullptr, N, SB,
        edge_ids, off, M, E);
    if (useBF)
        k_edge_agg<1><<<(E + 3) / 4, 256, 0, stream>>>(
            X, Xb, sarr, node_idx, off, outZ, outBeta, E);
    else
        k_edge_agg<0><<<(E + 3) / 4, 256, 0, stream>>>(
            X, Xb, sarr, node_idx, off, outZ, outBeta, E);
}